// Round 13
// baseline (4593.102 us; speedup 1.0000x reference)
//
#include <hip/hip_runtime.h>
#include <stdint.h>
#include <cstdio>

typedef unsigned short u16;
typedef __attribute__((ext_vector_type(8))) __bf16 bf16x8;
typedef __attribute__((ext_vector_type(4))) float f32x4;
typedef __attribute__((ext_vector_type(4))) int i32x4;

#define AGENT __HIP_MEMORY_SCOPE_AGENT

__device__ __forceinline__ float bf2f(u16 u) {
  unsigned int x = ((unsigned int)u) << 16;
  return __builtin_bit_cast(float, x);
}
__device__ __forceinline__ u16 f2bf(float f) {
  unsigned int x = __builtin_bit_cast(unsigned int, f);
  unsigned int r = (x + 0x7fffu + ((x >> 16) & 1u)) >> 16;
  return (u16)r;
}
__device__ __forceinline__ float sigm(float x) { return 1.f / (1.f + __expf(-x)); }
__device__ __forceinline__ float tanh_f(float x) { return 1.f - 2.f / (__expf(2.f * x) + 1.f); }

// ---------- fp32 -> bf16 convert (x) ----------
__global__ __launch_bounds__(256) void k_cvt(const float* __restrict__ in, u16* __restrict__ out, int n4) {
  int i = blockIdx.x * 256 + threadIdx.x;
  if (i >= n4) return;
  float4 f = ((const float4*)in)[i];
  ushort4 o;
  o.x = f2bf(f.x); o.y = f2bf(f.y); o.z = f2bf(f.z); o.w = f2bf(f.w);
  ((ushort4*)out)[i] = o;
}

// ---------- pack Wx [768][3072] -> B-fragment order [nt=192][kt=24][lane=64][j=8] ----------
__global__ __launch_bounds__(256) void k_pack_wx(const float* __restrict__ Wx, u16* __restrict__ Bp) {
  int idx = blockIdx.x * 256 + threadIdx.x;
  if (idx >= 2359296) return;
  int j = idx & 7;
  int l = (idx >> 3) & 63;
  int t = idx >> 9;          // nt*24 + kt
  int kt = t % 24, nt = t / 24;
  int k = kt * 32 + (l >> 4) * 8 + j;
  int n = nt * 16 + (l & 15);
  Bp[idx] = f2bf(Wx[(size_t)k * 3072 + n]);
}

// ---------- pack Wh -> per-member slices [w=16][nt=12][kt=24][lane=64][j=8] ----------
// member w owns 48 units; wave wv owns nt = {2wv, 2wv+1} (two 16-col tiles).
// col order within a tile: cc = 4*vi + q (vi = unit-in-tile 0..3, q = gate 0..3).
// unit = w*48 + (nt>>1)*8 + (nt&1)*4 + vi ; gcol = q*768 + unit  (A-operand of swapped MFMA)
__global__ __launch_bounds__(256) void k_pack_wh(const float* __restrict__ Wh, u16* __restrict__ Wp) {
  int idx = blockIdx.x * 256 + threadIdx.x;
  if (idx >= 2359296) return;
  int j = idx & 7;
  int l = (idx >> 3) & 63;
  int t = idx >> 9;          // (w*12 + nt)*24 + kt
  int kt = t % 24;
  int tmp = t / 24;          // w*12 + nt
  int nt = tmp % 12, w = tmp / 12;
  int k = kt * 32 + (l >> 4) * 8 + j;
  int cc = l & 15;
  int vi = cc >> 2, q = cc & 3;
  int unit = w * 48 + (nt >> 1) * 8 + (nt & 1) * 4 + vi;
  Wp[idx] = f2bf(Wh[(size_t)k * 3072 + q * 768 + unit]);
}

// ---------- GEMM: C[16384][3072] bf16 = A[16384][768] bf16 @ Bp(packed) ----------
__global__ __launch_bounds__(256, 2) void k_gemm(const u16* __restrict__ A, const u16* __restrict__ Bp,
                                                 u16* __restrict__ C) {
  const int bid = blockIdx.x;
  const int bm = bid & 127, bn = bid >> 7;   // 128 x 24
  const int tid = threadIdx.x, lane = tid & 63, wv = tid >> 6;
  const int wm = wv >> 1, wn = wv & 1;
  const int row0 = bm * 128 + wm * 64;
  const int col0 = bn * 128 + wn * 64;
  const int rlo = lane & 15, rhi = lane >> 4;
  f32x4 acc[4][4] = {};
  const u16* Ab = A + (size_t)(row0 + rlo) * 768 + rhi * 8;
  const u16* Bb = Bp + ((size_t)(bn * 8 + wn * 4) * 24 * 64 + lane) * 8;
#pragma unroll 2
  for (int kt = 0; kt < 24; ++kt) {
    bf16x8 a[4], b[4];
#pragma unroll
    for (int i = 0; i < 4; ++i) a[i] = *(const bf16x8*)(Ab + (size_t)i * 16 * 768 + kt * 32);
#pragma unroll
    for (int j = 0; j < 4; ++j) b[j] = *(const bf16x8*)(Bb + (size_t)j * 24 * 64 * 8 + (size_t)kt * 64 * 8);
#pragma unroll
    for (int i = 0; i < 4; ++i)
#pragma unroll
      for (int j = 0; j < 4; ++j)
        acc[i][j] = __builtin_amdgcn_mfma_f32_16x16x32_bf16(a[i], b[j], acc[i][j], 0, 0, 0);
  }
#pragma unroll
  for (int i = 0; i < 4; ++i)
#pragma unroll
    for (int j = 0; j < 4; ++j)
#pragma unroll
      for (int r = 0; r < 4; ++r) {
        int row = row0 + i * 16 + rhi * 4 + r;
        int col = col0 + j * 16 + rlo;
        C[(size_t)row * 3072 + col] = f2bf(acc[i][j][r]);
      }
}

// ---------- persistent LSTM recurrence ----------
// 128 WGs x 384 threads (6 waves), 1 WG/CU guaranteed resident. Logical groups: g = wid&7
// (4 seqs), member w = wid>>3 (0..15, 48 units each). Wave wv owns TWO 16-col tiles
// (units 8wv..8wv+7): 48 weight frags in regs; h-frags shared across both tiles.
// Per step: merged poll+fetch of tagged h_{t-1} (full load IS the poll, 1 LLC RT) -> B_A ->
// stage hlds -> B3 -> swapped MFMA D[cc][seq] (4 chains) -> cell math straight from acc
// (lane 16*vi + r owns cells (seq r, unit0/unit1)) -> fire-and-forget tagged publish.
__global__ __launch_bounds__(384) void k_rec(
    const u16* __restrict__ xg,    // [16384][3072] bf16, m = seq*512 + t
    const u16* __restrict__ Whp,   // [16][12][24][64][8] packed bf16
    const float* __restrict__ bias,
    int* hbuf,                     // [8 groups][2][3072] tagged dwords (zeroed)
    u16* __restrict__ hout_bf,     // layer 0 out (bf16) or null
    float* __restrict__ hout_f,    // layer 1 out (fp32) or null
    int layer) {
  __shared__ __align__(16) int hlds[4 * 400];   // h_{t-1}[4 seq][768] bf16, rows padded to 400 dw

  const int wid = blockIdx.x, g = wid & 7, w = wid >> 3;
  const int tid = threadIdx.x, lane = tid & 63, wv = tid >> 6;

  // ---- Wh fragments -> registers (static indices), two tiles per wave ----
  bf16x8 wE0[12], wO0[12], wE1[12], wO1[12];
  {
    const u16* bp0 = Whp + (((size_t)(w * 12 + wv * 2) * 24) * 64 + lane) * 8;
    const u16* bp1 = bp0 + (size_t)24 * 512;   // next nt (kt stride = 64*8 = 512 u16)
#pragma unroll
    for (int kk = 0; kk < 12; ++kk) {
      wE0[kk] = *(const bf16x8*)(bp0 + (size_t)(2 * kk) * 512);
      wO0[kk] = *(const bf16x8*)(bp0 + (size_t)(2 * kk + 1) * 512);
      wE1[kk] = *(const bf16x8*)(bp1 + (size_t)(2 * kk) * 512);
      wO1[kk] = *(const bf16x8*)(bp1 + (size_t)(2 * kk + 1) * 512);
    }
  }

  // ---- cell role: lane = 16*vi + r owns cells (seq r, unit0) and (seq r, unit1) ----
  const bool cellt = (lane & 15) < 4;
  const int vi = lane >> 4, r = lane & 3;
  const int unit0 = w * 48 + wv * 8 + vi;
  const int unit1 = unit0 + 4;
  const int seq = g * 4 + r;
  float bA0 = 0, bA1 = 0, bA2 = 0, bA3 = 0, bB0 = 0, bB1 = 0, bB2 = 0, bB3 = 0;
  float xA0 = 0, xA1 = 0, xA2 = 0, xA3 = 0, xB0 = 0, xB1 = 0, xB2 = 0, xB3 = 0;
  if (cellt) {
    bA0 = bias[unit0]; bA1 = bias[768 + unit0]; bA2 = bias[1536 + unit0]; bA3 = bias[2304 + unit0];
    bB0 = bias[unit1]; bB1 = bias[768 + unit1]; bB2 = bias[1536 + unit1]; bB3 = bias[2304 + unit1];
    const u16* xr = xg + (size_t)seq * 512 * 3072;
    xA0 = bf2f(xr[unit0]); xA1 = bf2f(xr[768 + unit0]);
    xA2 = bf2f(xr[1536 + unit0]); xA3 = bf2f(xr[2304 + unit0]);
    xB0 = bf2f(xr[unit1]); xB1 = bf2f(xr[768 + unit1]);
    xB2 = bf2f(xr[1536 + unit1]); xB3 = bf2f(xr[2304 + unit1]);
  }
  float cst0 = 0.f, cst1 = 0.f;
  const int sl = (lane & 15) < 4 ? (lane & 15) : 3;      // h-frag row (pad rows clamped)
  const int abase = sl * 400 + (lane >> 4) * 4;          // h-frag dword base in hlds
  const int c = tid;                                     // poll chunk id (8 dwords)
  const int hrow = c / 96, hcol = (c % 96) * 4;          // staged int4 slot
  int guard = 0;

  __syncthreads();

  for (int t = 0; t < 512; ++t) {
    // ---- merged poll+fetch of h_{t-1}: full tagged load IS the poll (1 RT) ----
    const int expect = t;  // tag written by step t-1 producers (t=0: zeroed buffer)
    int* src = hbuf + (size_t)(g * 2 + (t & 1)) * 3072;
    const int* p0 = src + 8 * c;
    const int* p1 = src + 8 * c + 4;
    i32x4 v0, v1;
    for (;;) {
      asm volatile("global_load_dwordx4 %0, %2, off sc0 sc1\n\t"
                   "global_load_dwordx4 %1, %3, off sc0 sc1\n\t"
                   "s_waitcnt vmcnt(0)"
                   : "=&v"(v0), "=&v"(v1)
                   : "v"(p0), "v"(p1)
                   : "memory");
      bool ok = true;
#pragma unroll
      for (int j = 0; j < 4; ++j)
        ok = ok && ((v0[j] & 0xffff) == expect) && ((v1[j] & 0xffff) == expect);
      if (ok || ++guard > (1 << 22)) break;
    }
    __syncthreads();  // B_A: all waves done reading hlds (MFMA of t-1)

    // stage packed bf16 pairs into hlds
    {
      int4 pk;
      pk.x = (int)(((unsigned)v0[0] >> 16) | ((unsigned)v0[1] & 0xffff0000u));
      pk.y = (int)(((unsigned)v0[2] >> 16) | ((unsigned)v0[3] & 0xffff0000u));
      pk.z = (int)(((unsigned)v1[0] >> 16) | ((unsigned)v1[1] & 0xffff0000u));
      pk.w = (int)(((unsigned)v1[2] >> 16) | ((unsigned)v1[3] & 0xffff0000u));
      *(int4*)&hlds[hrow * 400 + hcol] = pk;
    }
    __syncthreads();  // B3: hlds ready

    // ---- MFMA (swapped): D[cc][seq] = W(A) x h(B); 4 chains, h-frags shared ----
    f32x4 a0 = {0, 0, 0, 0}, a1 = {0, 0, 0, 0}, a2 = {0, 0, 0, 0}, a3 = {0, 0, 0, 0};
#pragma unroll
    for (int kk = 0; kk < 12; ++kk) {
      bf16x8 afe = *(const bf16x8*)(hlds + abase + (2 * kk) * 16);
      bf16x8 afo = *(const bf16x8*)(hlds + abase + (2 * kk + 1) * 16);
      a0 = __builtin_amdgcn_mfma_f32_16x16x32_bf16(wE0[kk], afe, a0, 0, 0, 0);
      a1 = __builtin_amdgcn_mfma_f32_16x16x32_bf16(wO0[kk], afo, a1, 0, 0, 0);
      a2 = __builtin_amdgcn_mfma_f32_16x16x32_bf16(wE1[kk], afe, a2, 0, 0, 0);
      a3 = __builtin_amdgcn_mfma_f32_16x16x32_bf16(wO1[kk], afo, a3, 0, 0, 0);
    }
    a0 += a1;  // tile0 gates: lane 16*vi + r has q=0..3 of (seq r, unit0)
    a2 += a3;  // tile1 gates: same lane, unit1

    if (cellt) {
      // cell 0 (unit0)
      float p0g = xA0 + a0[0] + bA0;
      float p1g = xA1 + a0[1] + bA1;
      float p2g = xA2 + a0[2] + bA2;
      float p3g = xA3 + a0[3] + bA3;
      float ig = sigm(p0g), fg = sigm(p1g), gg = tanh_f(p2g), og = sigm(p3g);
      cst0 = fg * cst0 + ig * gg;
      float h0 = og * tanh_f(cst0);
      // cell 1 (unit1)
      p0g = xB0 + a2[0] + bB0;
      p1g = xB1 + a2[1] + bB1;
      p2g = xB2 + a2[2] + bB2;
      p3g = xB3 + a2[3] + bB3;
      ig = sigm(p0g); fg = sigm(p1g); gg = tanh_f(p2g); og = sigm(p3g);
      cst1 = fg * cst1 + ig * gg;
      float h1 = og * tanh_f(cst1);
      // publish tagged h (fire-and-forget; dword atomicity self-validates)
      int* dstb = hbuf + (size_t)(g * 2 + ((t + 1) & 1)) * 3072 + r * 768;
      int val0 = (int)(((unsigned)f2bf(h0) << 16) | (unsigned)(t + 1));
      int val1 = (int)(((unsigned)f2bf(h1) << 16) | (unsigned)(t + 1));
      __hip_atomic_store(dstb + unit0, val0, __ATOMIC_RELAXED, AGENT);
      __hip_atomic_store(dstb + unit1, val1, __ATOMIC_RELAXED, AGENT);
      // off the critical path: output stores + next-step xg prefetch
      size_t ob = ((size_t)seq * 512 + t) * 768;
      if (layer == 0) {
        hout_bf[ob + unit0] = f2bf(h0);
        hout_bf[ob + unit1] = f2bf(h1);
      } else {
        hout_f[ob + unit0] = h0;
        hout_f[ob + unit1] = h1;
      }
      if (t + 1 < 512) {
        const u16* xr = xg + ((size_t)seq * 512 + t + 1) * 3072;
        xA0 = bf2f(xr[unit0]); xA1 = bf2f(xr[768 + unit0]);
        xA2 = bf2f(xr[1536 + unit0]); xA3 = bf2f(xr[2304 + unit0]);
        xB0 = bf2f(xr[unit1]); xB1 = bf2f(xr[768 + unit1]);
        xB2 = bf2f(xr[1536 + unit1]); xB3 = bf2f(xr[2304 + unit1]);
      }
    }
  }
}

// ---------- LayerNorm (in-place safe) ----------
__global__ __launch_bounds__(256) void k_ln(const float* __restrict__ in, const float* __restrict__ sc,
                                            const float* __restrict__ bi, float* __restrict__ out) {
  const int row = blockIdx.x, tid = threadIdx.x;
  const float* x = in + (size_t)row * 768;
  float v0 = x[tid], v1 = x[tid + 256], v2 = x[tid + 512];
  float s = v0 + v1 + v2;
  float s2 = v0 * v0 + v1 * v1 + v2 * v2;
#pragma unroll
  for (int off = 32; off >= 1; off >>= 1) {
    s += __shfl_xor(s, off);
    s2 += __shfl_xor(s2, off);
  }
  __shared__ float red[8];
  const int wv = tid >> 6;
  if ((tid & 63) == 0) { red[wv] = s; red[4 + wv] = s2; }
  __syncthreads();
  s = red[0] + red[1] + red[2] + red[3];
  s2 = red[4] + red[5] + red[6] + red[7];
  float mean = s * (1.f / 768.f);
  float var = s2 * (1.f / 768.f) - mean * mean;
  float rs = rsqrtf(var + 1e-6f);
  float* o = out + (size_t)row * 768;
  o[tid] = (v0 - mean) * rs * sc[tid] + bi[tid];
  o[tid + 256] = (v1 - mean) * rs * sc[tid + 256] + bi[tid + 256];
  o[tid + 512] = (v2 - mean) * rs * sc[tid + 512] + bi[tid + 512];
}

extern "C" void kernel_launch(void* const* d_in, const int* in_sizes, int n_in,
                              void* d_out, int out_size, void* d_ws, size_t ws_size,
                              hipStream_t stream) {
  const float* x   = (const float*)d_in[0];
  const float* Wx0 = (const float*)d_in[1];
  const float* Wh0 = (const float*)d_in[2];
  const float* b0  = (const float*)d_in[3];
  const float* Wx1 = (const float*)d_in[4];
  const float* Wh1 = (const float*)d_in[5];
  const float* b1  = (const float*)d_in[6];
  const float* lns = (const float*)d_in[7];
  const float* lnb = (const float*)d_in[8];
  float* out = (float*)d_out;

  char* p = (char*)d_ws;
  auto alloc = [&](size_t bytes) {
    char* r = p;
    p += (bytes + 255) & ~(size_t)255;
    return r;
  };
  u16* xg    = (u16*)alloc(16384ull * 3072 * 2);
  u16* xbf   = (u16*)alloc(16384ull * 768 * 2);
  u16* h0bf  = (u16*)alloc(16384ull * 768 * 2);
  u16* Wxp0  = (u16*)alloc(2359296ull * 2);
  u16* Wxp1  = (u16*)alloc(2359296ull * 2);
  u16* Whp0  = (u16*)alloc(2359296ull * 2);
  u16* Whp1  = (u16*)alloc(2359296ull * 2);
  char* sync0 = alloc(196608ull * 2);   // hbuf0, hbuf1 (tagged dwords)
  int* hbuf0 = (int*)sync0;
  int* hbuf1 = (int*)(sync0 + 196608);

  if ((size_t)(p - (char*)d_ws) > ws_size) {
    fprintf(stderr, "kernel_launch: ws too small: need %zu have %zu\n",
            (size_t)(p - (char*)d_ws), ws_size);
    return;
  }

  hipMemsetAsync(sync0, 0, 196608ull * 2, stream);
  k_cvt<<<12288, 256, 0, stream>>>(x, xbf, 3145728);
  k_pack_wx<<<9216, 256, 0, stream>>>(Wx0, Wxp0);
  k_pack_wx<<<9216, 256, 0, stream>>>(Wx1, Wxp1);
  k_pack_wh<<<9216, 256, 0, stream>>>(Wh0, Whp0);
  k_pack_wh<<<9216, 256, 0, stream>>>(Wh1, Whp1);

  k_gemm<<<3072, 256, 0, stream>>>(xbf, Wxp0, xg);
  k_rec<<<128, 384, 0, stream>>>(xg, Whp0, b0, hbuf0, h0bf, nullptr, 0);
  k_gemm<<<3072, 256, 0, stream>>>(h0bf, Wxp1, xg);
  k_rec<<<128, 384, 0, stream>>>(xg, Whp1, b1, hbuf1, nullptr, (float*)d_out, 1);
  k_ln<<<16384, 256, 0, stream>>>((const float*)d_out, lns, lnb, out);
}

// Round 14
// 2141.838 us; speedup vs baseline: 2.1445x; 2.1445x over previous
//
#include <hip/hip_runtime.h>
#include <stdint.h>
#include <cstdio>

typedef unsigned short u16;
typedef __attribute__((ext_vector_type(8))) __bf16 bf16x8;
typedef __attribute__((ext_vector_type(4))) float f32x4;
typedef __attribute__((ext_vector_type(4))) int i32x4;

#define AGENT __HIP_MEMORY_SCOPE_AGENT

__device__ __forceinline__ float bf2f(u16 u) {
  unsigned int x = ((unsigned int)u) << 16;
  return __builtin_bit_cast(float, x);
}
__device__ __forceinline__ u16 f2bf(float f) {
  unsigned int x = __builtin_bit_cast(unsigned int, f);
  unsigned int r = (x + 0x7fffu + ((x >> 16) & 1u)) >> 16;
  return (u16)r;
}
__device__ __forceinline__ float sigm(float x) { return 1.f / (1.f + __expf(-x)); }
__device__ __forceinline__ float tanh_f(float x) { return 1.f - 2.f / (__expf(2.f * x) + 1.f); }

// ---------- fp32 -> bf16 convert (x) ----------
__global__ __launch_bounds__(256) void k_cvt(const float* __restrict__ in, u16* __restrict__ out, int n4) {
  int i = blockIdx.x * 256 + threadIdx.x;
  if (i >= n4) return;
  float4 f = ((const float4*)in)[i];
  ushort4 o;
  o.x = f2bf(f.x); o.y = f2bf(f.y); o.z = f2bf(f.z); o.w = f2bf(f.w);
  ((ushort4*)out)[i] = o;
}

// ---------- pack Wx [768][3072] -> B-fragment order [nt=192][kt=24][lane=64][j=8] ----------
__global__ __launch_bounds__(256) void k_pack_wx(const float* __restrict__ Wx, u16* __restrict__ Bp) {
  int idx = blockIdx.x * 256 + threadIdx.x;
  if (idx >= 2359296) return;
  int j = idx & 7;
  int l = (idx >> 3) & 63;
  int t = idx >> 9;          // nt*24 + kt
  int kt = t % 24, nt = t / 24;
  int k = kt * 32 + (l >> 4) * 8 + j;
  int n = nt * 16 + (l & 15);
  Bp[idx] = f2bf(Wx[(size_t)k * 3072 + n]);
}

// ---------- pack Wh -> per-member slices [w=32][nt=6][kt=24][lane=64][j=8] ----------
// col order within 16-col tile: cc = 4*vi + q (vi = unit-in-wave 0..3, q = gate 0..3)
// Serves as the A-operand (rows = cc) of the swapped MFMA.
__global__ __launch_bounds__(256) void k_pack_wh(const float* __restrict__ Wh, u16* __restrict__ Wp) {
  int idx = blockIdx.x * 256 + threadIdx.x;
  if (idx >= 2359296) return;
  int j = idx & 7;
  int l = (idx >> 3) & 63;
  int t = idx >> 9;          // w*144 + nt*24 + kt
  int kt = t % 24;
  int tmp = t / 24;          // w*6 + nt
  int nt = tmp % 6, w = tmp / 6;
  int k = kt * 32 + (l >> 4) * 8 + j;
  int cc = l & 15;
  int vi = cc >> 2, q = cc & 3;
  int gcol = q * 768 + w * 24 + nt * 4 + vi;
  Wp[idx] = f2bf(Wh[(size_t)k * 3072 + gcol]);
}

// ---------- GEMM: C[16384][3072] bf16 = A[16384][768] bf16 @ Bp(packed) ----------
__global__ __launch_bounds__(256, 2) void k_gemm(const u16* __restrict__ A, const u16* __restrict__ Bp,
                                                 u16* __restrict__ C) {
  const int bid = blockIdx.x;
  const int bm = bid & 127, bn = bid >> 7;   // 128 x 24
  const int tid = threadIdx.x, lane = tid & 63, wv = tid >> 6;
  const int wm = wv >> 1, wn = wv & 1;
  const int row0 = bm * 128 + wm * 64;
  const int col0 = bn * 128 + wn * 64;
  const int rlo = lane & 15, rhi = lane >> 4;
  f32x4 acc[4][4] = {};
  const u16* Ab = A + (size_t)(row0 + rlo) * 768 + rhi * 8;
  const u16* Bb = Bp + ((size_t)(bn * 8 + wn * 4) * 24 * 64 + lane) * 8;
#pragma unroll 2
  for (int kt = 0; kt < 24; ++kt) {
    bf16x8 a[4], b[4];
#pragma unroll
    for (int i = 0; i < 4; ++i) a[i] = *(const bf16x8*)(Ab + (size_t)i * 16 * 768 + kt * 32);
#pragma unroll
    for (int j = 0; j < 4; ++j) b[j] = *(const bf16x8*)(Bb + (size_t)j * 24 * 64 * 8 + (size_t)kt * 64 * 8);
#pragma unroll
    for (int i = 0; i < 4; ++i)
#pragma unroll
      for (int j = 0; j < 4; ++j)
        acc[i][j] = __builtin_amdgcn_mfma_f32_16x16x32_bf16(a[i], b[j], acc[i][j], 0, 0, 0);
  }
#pragma unroll
  for (int i = 0; i < 4; ++i)
#pragma unroll
    for (int j = 0; j < 4; ++j)
#pragma unroll
      for (int r = 0; r < 4; ++r) {
        int row = row0 + i * 16 + rhi * 4 + r;
        int col = col0 + j * 16 + rlo;
        C[(size_t)row * 3072 + col] = f2bf(acc[i][j][r]);
      }
}

// ---------- persistent LSTM recurrence ----------
// 256 WGs x 384 threads (6 waves) — R12-proven base. Logical groups: g = wid&7 (4 seqs),
// member w = wid>>3 (24 units). Wave wv owns one 16-col tile = 4 gates x 4 units.
// NEW: weight frags loaded via inline-asm global_load_dwordx4 -> compiler CANNOT
// rematerialize/sink them; all 24 frags (96 VGPRs) stay register-resident across the
// 512-step loop, eliminating the per-step 147 KB L1/L2 weight re-stream.
// Per step: merged poll+fetch of tagged h_{t-1} (full load IS the poll, 1 LLC RT) -> B_A ->
// stage hlds -> B3 -> swapped MFMA D[cc][seq] (lane 16*vi + r holds all 4 gates of cell
// (seq r, unit vi)) -> cell math from acc -> fire-and-forget tagged publish, parity dbuf.
__global__ __launch_bounds__(384) void k_rec(
    const u16* __restrict__ xg,    // [16384][3072] bf16, m = seq*512 + t
    const u16* __restrict__ Whp,   // [32][6][24][64][8] packed bf16
    const float* __restrict__ bias,
    int* hbuf,                     // [8 groups][2][3072] tagged dwords (zeroed)
    u16* __restrict__ hout_bf,     // layer 0 out (bf16) or null
    float* __restrict__ hout_f,    // layer 1 out (fp32) or null
    int layer) {
  __shared__ __align__(16) int hlds[4 * 400];   // h_{t-1}[4 seq][768] bf16, rows padded to 400 dw

  const int wid = blockIdx.x, g = wid & 7, w = wid >> 3;
  const int tid = threadIdx.x, lane = tid & 63, wv = tid >> 6;

  // ---- Wh fragments -> registers, FORCED resident (asm loads can't be rematerialized) ----
  i32x4 wE[12], wO[12];
  {
    const u16* bp = Whp + (((size_t)(w * 6 + wv) * 24) * 64 + lane) * 8;
#pragma unroll
    for (int kk = 0; kk < 12; ++kk) {
      const u16* pe = bp + (size_t)(2 * kk) * 512;
      const u16* po = bp + (size_t)(2 * kk + 1) * 512;
      asm volatile("global_load_dwordx4 %0, %2, off\n\t"
                   "global_load_dwordx4 %1, %3, off"
                   : "=&v"(wE[kk]), "=&v"(wO[kk])
                   : "v"(pe), "v"(po));
    }
    asm volatile("s_waitcnt vmcnt(0)");
  }

  // ---- cell role: lane = 16*vi + r owns cell (seq r, unit vi) ----
  const bool cellt = (lane & 15) < 4;
  const int vi = lane >> 4, r = lane & 3;
  const int unit = w * 24 + wv * 4 + vi;
  const int seq = g * 4 + r;
  float bv0 = 0, bv1 = 0, bv2 = 0, bv3 = 0, xv0 = 0, xv1 = 0, xv2 = 0, xv3 = 0;
  if (cellt) {
    bv0 = bias[unit]; bv1 = bias[768 + unit]; bv2 = bias[1536 + unit]; bv3 = bias[2304 + unit];
    const u16* xr = xg + (size_t)seq * 512 * 3072;
    xv0 = bf2f(xr[unit]); xv1 = bf2f(xr[768 + unit]);
    xv2 = bf2f(xr[1536 + unit]); xv3 = bf2f(xr[2304 + unit]);
  }
  float cst = 0.f;
  const int sl = (lane & 15) < 4 ? (lane & 15) : 3;      // h-frag row (pad rows clamped)
  const int abase = sl * 400 + (lane >> 4) * 4;          // h-frag dword base in hlds
  // poll/stage role: thread tid handles 8 tagged dwords
  const int c = tid;                                     // 0..383
  const int hrow = c / 96, hcol = (c % 96) * 4;          // packed int4 slot in hlds
  int guard = 0;

  __syncthreads();

  for (int t = 0; t < 512; ++t) {
    // ---- merged poll+fetch of h_{t-1}: full tagged load IS the poll (1 RT) ----
    const int expect = t;  // tag written by step t-1 producers (t=0: zeroed buffer)
    int* src = hbuf + (size_t)(g * 2 + (t & 1)) * 3072;
    const int* p0 = src + 8 * c;
    const int* p1 = src + 8 * c + 4;
    i32x4 v0, v1;
    for (;;) {
      asm volatile("global_load_dwordx4 %0, %2, off sc0 sc1\n\t"
                   "global_load_dwordx4 %1, %3, off sc0 sc1\n\t"
                   "s_waitcnt vmcnt(0)"
                   : "=&v"(v0), "=&v"(v1)
                   : "v"(p0), "v"(p1)
                   : "memory");
      bool ok = true;
#pragma unroll
      for (int j = 0; j < 4; ++j)
        ok = ok && ((v0[j] & 0xffff) == expect) && ((v1[j] & 0xffff) == expect);
      if (ok || ++guard > (1 << 22)) break;
    }
    __syncthreads();  // B_A: all waves done reading hlds (MFMA of t-1)

    // stage packed bf16 pairs into hlds
    {
      int4 pk;
      pk.x = (int)(((unsigned)v0[0] >> 16) | ((unsigned)v0[1] & 0xffff0000u));
      pk.y = (int)(((unsigned)v0[2] >> 16) | ((unsigned)v0[3] & 0xffff0000u));
      pk.z = (int)(((unsigned)v1[0] >> 16) | ((unsigned)v1[1] & 0xffff0000u));
      pk.w = (int)(((unsigned)v1[2] >> 16) | ((unsigned)v1[3] & 0xffff0000u));
      *(int4*)&hlds[hrow * 400 + hcol] = pk;
    }
    __syncthreads();  // B3: hlds ready

    // ---- MFMA (swapped): D[cc][seq] = W(A) x h(B), kt-parity 2 chains ----
    f32x4 a0 = {0, 0, 0, 0}, a1 = {0, 0, 0, 0};
#pragma unroll
    for (int kk = 0; kk < 12; ++kk) {
      bf16x8 afe = *(const bf16x8*)(hlds + abase + (2 * kk) * 16);
      bf16x8 afo = *(const bf16x8*)(hlds + abase + (2 * kk + 1) * 16);
      a0 = __builtin_amdgcn_mfma_f32_16x16x32_bf16(__builtin_bit_cast(bf16x8, wE[kk]), afe, a0, 0, 0, 0);
      a1 = __builtin_amdgcn_mfma_f32_16x16x32_bf16(__builtin_bit_cast(bf16x8, wO[kk]), afo, a1, 0, 0, 0);
    }
    a0 += a1;
    // D layout: row = cc = (lane>>4)*4 + reg, col = seq = lane&15
    // -> lane 16*vi + r holds gates q=0..3 (i,f,g,o) of cell (seq r, unit vi) in a0[0..3]

    if (cellt) {
      float p0g = xv0 + a0[0] + bv0;
      float p1g = xv1 + a0[1] + bv1;
      float p2g = xv2 + a0[2] + bv2;
      float p3g = xv3 + a0[3] + bv3;
      float ig = sigm(p0g), fg = sigm(p1g), gg = tanh_f(p2g), og = sigm(p3g);
      cst = fg * cst + ig * gg;
      float h = og * tanh_f(cst);
      // publish tagged h (fire-and-forget; dword atomicity makes it self-validating)
      int* dst = hbuf + (size_t)(g * 2 + ((t + 1) & 1)) * 3072 + r * 768 + unit;
      int val = (int)(((unsigned)f2bf(h) << 16) | (unsigned)(t + 1));
      __hip_atomic_store(dst, val, __ATOMIC_RELAXED, AGENT);
      // off the critical path: output store + next-step xg prefetch
      size_t o = ((size_t)seq * 512 + t) * 768 + unit;
      if (layer == 0) hout_bf[o] = f2bf(h); else hout_f[o] = h;
      if (t + 1 < 512) {
        const u16* xr = xg + ((size_t)seq * 512 + t + 1) * 3072;
        xv0 = bf2f(xr[unit]); xv1 = bf2f(xr[768 + unit]);
        xv2 = bf2f(xr[1536 + unit]); xv3 = bf2f(xr[2304 + unit]);
      }
    }
  }
}

// ---------- LayerNorm (in-place safe) ----------
__global__ __launch_bounds__(256) void k_ln(const float* __restrict__ in, const float* __restrict__ sc,
                                            const float* __restrict__ bi, float* __restrict__ out) {
  const int row = blockIdx.x, tid = threadIdx.x;
  const float* x = in + (size_t)row * 768;
  float v0 = x[tid], v1 = x[tid + 256], v2 = x[tid + 512];
  float s = v0 + v1 + v2;
  float s2 = v0 * v0 + v1 * v1 + v2 * v2;
#pragma unroll
  for (int off = 32; off >= 1; off >>= 1) {
    s += __shfl_xor(s, off);
    s2 += __shfl_xor(s2, off);
  }
  __shared__ float red[8];
  const int wv = tid >> 6;
  if ((tid & 63) == 0) { red[wv] = s; red[4 + wv] = s2; }
  __syncthreads();
  s = red[0] + red[1] + red[2] + red[3];
  s2 = red[4] + red[5] + red[6] + red[7];
  float mean = s * (1.f / 768.f);
  float var = s2 * (1.f / 768.f) - mean * mean;
  float rs = rsqrtf(var + 1e-6f);
  float* o = out + (size_t)row * 768;
  o[tid] = (v0 - mean) * rs * sc[tid] + bi[tid];
  o[tid + 256] = (v1 - mean) * rs * sc[tid + 256] + bi[tid + 256];
  o[tid + 512] = (v2 - mean) * rs * sc[tid + 512] + bi[tid + 512];
}

extern "C" void kernel_launch(void* const* d_in, const int* in_sizes, int n_in,
                              void* d_out, int out_size, void* d_ws, size_t ws_size,
                              hipStream_t stream) {
  const float* x   = (const float*)d_in[0];
  const float* Wx0 = (const float*)d_in[1];
  const float* Wh0 = (const float*)d_in[2];
  const float* b0  = (const float*)d_in[3];
  const float* Wx1 = (const float*)d_in[4];
  const float* Wh1 = (const float*)d_in[5];
  const float* b1  = (const float*)d_in[6];
  const float* lns = (const float*)d_in[7];
  const float* lnb = (const float*)d_in[8];
  float* out = (float*)d_out;

  char* p = (char*)d_ws;
  auto alloc = [&](size_t bytes) {
    char* r = p;
    p += (bytes + 255) & ~(size_t)255;
    return r;
  };
  u16* xg    = (u16*)alloc(16384ull * 3072 * 2);
  u16* xbf   = (u16*)alloc(16384ull * 768 * 2);
  u16* h0bf  = (u16*)alloc(16384ull * 768 * 2);
  u16* Wxp0  = (u16*)alloc(2359296ull * 2);
  u16* Wxp1  = (u16*)alloc(2359296ull * 2);
  u16* Whp0  = (u16*)alloc(2359296ull * 2);
  u16* Whp1  = (u16*)alloc(2359296ull * 2);
  char* sync0 = alloc(196608ull * 2);   // hbuf0, hbuf1 (tagged dwords)
  int* hbuf0 = (int*)sync0;
  int* hbuf1 = (int*)(sync0 + 196608);

  if ((size_t)(p - (char*)d_ws) > ws_size) {
    fprintf(stderr, "kernel_launch: ws too small: need %zu have %zu\n",
            (size_t)(p - (char*)d_ws), ws_size);
    return;
  }

  hipMemsetAsync(sync0, 0, 196608ull * 2, stream);
  k_cvt<<<12288, 256, 0, stream>>>(x, xbf, 3145728);
  k_pack_wx<<<9216, 256, 0, stream>>>(Wx0, Wxp0);
  k_pack_wx<<<9216, 256, 0, stream>>>(Wx1, Wxp1);
  k_pack_wh<<<9216, 256, 0, stream>>>(Wh0, Whp0);
  k_pack_wh<<<9216, 256, 0, stream>>>(Wh1, Whp1);

  k_gemm<<<3072, 256, 0, stream>>>(xbf, Wxp0, xg);
  k_rec<<<256, 384, 0, stream>>>(xg, Whp0, b0, hbuf0, h0bf, nullptr, 0);
  k_gemm<<<3072, 256, 0, stream>>>(h0bf, Wxp1, xg);
  k_rec<<<256, 384, 0, stream>>>(xg, Whp1, b1, hbuf1, nullptr, (float*)d_out, 1);
  k_ln<<<16384, 256, 0, stream>>>((const float*)d_out, lns, lnb, out);
}